// Round 7
// baseline (373.600 us; speedup 1.0000x reference)
//
#include <hip/hip_runtime.h>

#define NI 50000
#define E_INTN 500000
#define E_BN 20000
#define E_CN 10000
#define E_TOT (E_INTN + E_BN + E_CN)

typedef __attribute__((ext_vector_type(8))) short bf16x8_t;
typedef __attribute__((ext_vector_type(4))) float f32x4_t;

__device__ __forceinline__ unsigned short f2bf(float f) {
    unsigned int u = __float_as_uint(f);
    unsigned int r = (u + 0x7FFFu + ((u >> 16) & 1u)) >> 16;
    return (unsigned short)r;
}
__device__ __forceinline__ float bf2f(unsigned int h) {
    return __uint_as_float(h << 16);
}

// async global->LDS, 16B per lane; LDS dest = wave-uniform base + lane*16
__device__ __forceinline__ void gload16(const unsigned short* g, unsigned short* l) {
    __builtin_amdgcn_global_load_lds(
        (const __attribute__((address_space(1))) void*)g,
        (__attribute__((address_space(3))) void*)l, 16, 0, 0);
}

// ---------------------------------------------------------------------------
// prep: fp32->bf16 conversion, weight packing, fp32 weight-combine GEMMs
// (G_* = W_im@W_*src etc. -- exact fp32 dot, single bf16 rounding), bias
// combine vectors, and edge counting. Counts zeroed by hipMemsetAsync first.
struct WJob { const float* src; int stride, off, off2, N, K, dstOff; };
struct WJobs { WJob j[3]; };
struct CJob { const float* L; const float* R; int rstr, roff, roff2, N, dstOff; };
struct CJobs { CJob j[8]; };
struct BiasArgs {
    const float *W_im, *W_bm, *W_cm;
    const float *b_ii, *b_bi, *b_ci, *b_bb, *b_cc;
    const float *b_is, *b_im, *b_bs, *b_bm, *b_cs, *b_cm;
};

#define CONV_NB 9375   // (2400000+255)/256 float4-groups
#define PW_NB   384    // 3 pack jobs x 128 blocks
#define CMB_NB  1024   // 8 combine jobs x 128 blocks
#define CNT_NB  2071   // ceil(530000/256)
#define PREP_NB (CONV_NB + PW_NB + 1 + CMB_NB + CNT_NB)

__global__ __launch_bounds__(256) void prep_kernel(
    const float4* __restrict__ x, const float4* __restrict__ xb,
    const float4* __restrict__ u,
    ushort4* __restrict__ x_bf, ushort4* __restrict__ xb_bf,
    ushort4* __restrict__ u_bf,
    WJobs jobs, CJobs cjobs, BiasArgs ba,
    unsigned short* __restrict__ wbuf,
    const int* __restrict__ ei, const int* __restrict__ eb,
    const int* __restrict__ ec, const int* __restrict__ bidx,
    const int* __restrict__ cidx,
    int* __restrict__ ci, int* __restrict__ cb, int* __restrict__ cc,
    float* __restrict__ bias) {
    int b = blockIdx.x;
    int tid = threadIdx.x;
    if (b < CONV_NB) {
        int g = b * 256 + tid;
        const float4* src; ushort4* dst; int i;
        if (g < 1600000)      { src = x;  dst = x_bf;  i = g; }
        else if (g < 2240000) { src = xb; dst = xb_bf; i = g - 1600000; }
        else if (g < 2400000) { src = u;  dst = u_bf;  i = g - 2240000; }
        else return;
        float4 v = src[i];
        ushort4 o;
        o.x = f2bf(v.x); o.y = f2bf(v.y); o.z = f2bf(v.z); o.w = f2bf(v.w);
        dst[i] = o;
    } else if (b < CONV_NB + PW_NB) {
        int lb = b - CONV_NB;
        WJob jb = jobs.j[lb >> 7];
        int idx = (lb & 127) * 256 + tid;
        if (idx >= jb.N * jb.K) return;
        int n = idx / jb.K;
        int k = idx - n * jb.K;
        float v = jb.src[(size_t)n * jb.stride + jb.off + k];
        if (jb.off2 >= 0) v += jb.src[(size_t)n * jb.stride + jb.off2 + k];
        wbuf[jb.dstOff + (size_t)n * jb.K + k] = f2bf(v);
    } else if (b == CONV_NB + PW_NB) {
        // bias combines (fp32 dots): biasI/B/C + cI0..2
        int t = tid;
        float a0 = 0.f, a1 = 0.f, a2 = 0.f, ab = 0.f, ac = 0.f;
        for (int k = 0; k < 128; ++k) {
            float wim = ba.W_im[t * 128 + k];
            a0 += wim * ba.b_ii[k];
            a1 += wim * ba.b_bi[k];
            a2 += wim * ba.b_ci[k];
            ab += ba.W_bm[t * 128 + k] * ba.b_bb[k];
            ac += ba.W_cm[t * 128 + k] * ba.b_cc[k];
        }
        bias[t]        = ba.b_is[t] + ba.b_im[t];
        bias[256 + t]  = ba.b_bs[t] + ba.b_bm[t] + ab;
        bias[512 + t]  = ba.b_cs[t] + ba.b_cm[t] + ac;
        bias[768 + t]  = a0;
        bias[1024 + t] = a1;
        bias[1280 + t] = a2;
    } else if (b < CONV_NB + PW_NB + 1 + CMB_NB) {
        int lb = b - CONV_NB - PW_NB - 1;
        CJob cj = cjobs.j[lb >> 7];
        int idx = (lb & 127) * 256 + tid;
        if (idx >= 256 * cj.N) return;
        int h = (cj.N == 128) ? (idx >> 7) : (idx >> 6);
        int d = idx & (cj.N - 1);
        const float* Lr = cj.L + (size_t)h * 128;
        float v = 0.f;
        if (cj.roff2 >= 0) {
            for (int k = 0; k < 128; ++k)
                v += Lr[k] * (cj.R[(size_t)k * cj.rstr + cj.roff + d] +
                              cj.R[(size_t)k * cj.rstr + cj.roff2 + d]);
        } else {
            for (int k = 0; k < 128; ++k)
                v += Lr[k] * cj.R[(size_t)k * cj.rstr + cj.roff + d];
        }
        wbuf[cj.dstOff + (size_t)h * cj.N + d] = f2bf(v);
    } else {
        int e = (b - CONV_NB - PW_NB - 1 - CMB_NB) * 256 + tid;
        if (e < E_INTN) {
            atomicAdd(&ci[ei[E_INTN + e]], 1);
        } else if (e < E_INTN + E_BN) {
            int j = e - E_INTN;
            int s = eb[j];
            bool m = false;
#pragma unroll
            for (int k = 0; k < 16; ++k) m = m || (s == bidx[k]);
            if (m) atomicAdd(&cb[eb[E_BN + j]], 1);
        } else if (e < E_TOT) {
            int j = e - E_INTN - E_BN;
            int s = ec[j];
            bool m = false;
#pragma unroll
            for (int k = 0; k < 16; ++k) m = m || (s == cidx[k]);
            if (m) atomicAdd(&cc[ec[E_CN + j]], 1);
        }
    }
}

// ---------------------------------------------------------------------------
#define SCAN_NB 196   // ceil(50000/256)

__global__ __launch_bounds__(256) void scan1_kernel(const int* __restrict__ ci,
                                                    const int* __restrict__ cb,
                                                    const int* __restrict__ cc,
                                                    int* __restrict__ bsum) {
    __shared__ int sm[256];
    int n = blockIdx.x * 256 + threadIdx.x;
    int d = (n < NI) ? ci[n] + cb[n] + cc[n] : 0;
    sm[threadIdx.x] = d;
    __syncthreads();
    for (int s = 128; s > 0; s >>= 1) {
        if (threadIdx.x < s) sm[threadIdx.x] += sm[threadIdx.x + s];
        __syncthreads();
    }
    if (threadIdx.x == 0) bsum[blockIdx.x] = sm[0];
}

__global__ __launch_bounds__(256) void scan23_kernel(const int* __restrict__ ci,
                                                     const int* __restrict__ cb,
                                                     const int* __restrict__ cc,
                                                     const int* __restrict__ bsum,
                                                     int* __restrict__ offsets,
                                                     int* __restrict__ cursor) {
    __shared__ int bs[256];
    __shared__ int sm[256];
    int t = threadIdx.x;
    int b = blockIdx.x;
    bs[t] = (t < b) ? bsum[t] : 0;
    __syncthreads();
    for (int s = 128; s > 0; s >>= 1) {
        if (t < s) bs[t] += bs[t + s];
        __syncthreads();
    }
    int ebase = bs[0];
    int n = b * 256 + t;
    int d = (n < NI) ? ci[n] + cb[n] + cc[n] : 0;
    sm[t] = d;
    __syncthreads();
    for (int dd = 1; dd < 256; dd <<= 1) {
        int v = (t >= dd) ? sm[t - dd] : 0;
        __syncthreads();
        sm[t] += v;
        __syncthreads();
    }
    if (n < NI) {
        int excl = sm[t] - d + ebase;
        offsets[n] = excl;
        cursor[n] = excl;
    }
}

// ---------------------------------------------------------------------------
__global__ __launch_bounds__(256) void fill_kernel(const int* __restrict__ ei,
                                                   const int* __restrict__ eb,
                                                   const int* __restrict__ ec,
                                                   const int* __restrict__ bidx,
                                                   const int* __restrict__ cidx,
                                                   int* __restrict__ cursor,
                                                   int* __restrict__ eids) {
    int e = blockIdx.x * 256 + threadIdx.x;
    int t, payload;
    if (e < E_INTN) {
        t = ei[E_INTN + e];
        payload = ei[e];
    } else if (e < E_INTN + E_BN) {
        int j = e - E_INTN;
        int s = eb[j];
        bool m = false;
#pragma unroll
        for (int k = 0; k < 16; ++k) m = m || (s == bidx[k]);
        if (!m) return;
        t = eb[E_BN + j];
        payload = NI + j;
    } else if (e < E_TOT) {
        int j = e - E_INTN - E_BN;
        int s = ec[j];
        bool m = false;
#pragma unroll
        for (int k = 0; k < 16; ++k) m = m || (s == cidx[k]);
        if (!m) return;
        t = ec[E_CN + j];
        payload = NI + E_BN + j;
    } else {
        return;
    }
    int idx = atomicAdd(&cursor[t], 1);
    eids[idx] = payload;
}

// ---------------------------------------------------------------------------
// gather (raw-input form): sums RAW bf16 source rows per edge type into
// three accumulators, writes pre-divided sums [sx(128)|sb(128)|su(64)]
// (stride 320) + per-node fp32 scales rs = {di,db,dc}/deg'. Source region
// is x_bf (12.8MB, L2/L3-hot) instead of the old 67MB Y buffers.
__global__ __launch_bounds__(256) void gather_kernel(
    const unsigned short* __restrict__ x_bf,
    const unsigned short* __restrict__ xb_bf,
    const unsigned short* __restrict__ u_bf,
    const int* __restrict__ offsets,
    const int* __restrict__ ci, const int* __restrict__ cb,
    const int* __restrict__ cc, const int* __restrict__ eids,
    unsigned short* __restrict__ agg, float* __restrict__ rs) {
    int g = blockIdx.x * 256 + threadIdx.x;
    int n = g >> 4;
    int lane = g & 15;
    if (n >= NI) return;
    int off = offsets[n];
    int di = ci[n], db = cb[n], dc = cc[n];
    int deg = di + db + dc;
    float ax[8], bx[8], ux[8];
#pragma unroll
    for (int i = 0; i < 8; ++i) { ax[i] = 0.f; bx[i] = 0.f; ux[i] = 0.f; }

    auto eptr = [&](int eid) -> const unsigned short* {
        return (eid < NI) ? x_bf + (size_t)eid * 128 + lane * 8
             : (eid < NI + E_BN) ? xb_bf + (size_t)(eid - NI) * 128 + lane * 8
             : u_bf + (size_t)(eid - NI - E_BN) * 64 + (lane & 7) * 8;
    };
    auto acc3 = [&](uint4 d, int eid) {
        float w0 = (eid < NI) ? 1.f : 0.f;
        float w1 = (eid >= NI && eid < NI + E_BN) ? 1.f : 0.f;
        float w2 = (eid >= NI + E_BN && lane < 8) ? 1.f : 0.f;
        float v[8];
        v[0] = bf2f(d.x & 0xffff); v[1] = bf2f(d.x >> 16);
        v[2] = bf2f(d.y & 0xffff); v[3] = bf2f(d.y >> 16);
        v[4] = bf2f(d.z & 0xffff); v[5] = bf2f(d.z >> 16);
        v[6] = bf2f(d.w & 0xffff); v[7] = bf2f(d.w >> 16);
#pragma unroll
        for (int i = 0; i < 8; ++i) {
            ax[i] += w0 * v[i]; bx[i] += w1 * v[i]; ux[i] += w2 * v[i];
        }
    };

    int k = 0;
    for (; k + 4 <= deg; k += 4) {
        int e0 = eids[off + k],     e1 = eids[off + k + 1];
        int e2 = eids[off + k + 2], e3 = eids[off + k + 3];
        const unsigned short* p0 = eptr(e0);
        const unsigned short* p1 = eptr(e1);
        const unsigned short* p2 = eptr(e2);
        const unsigned short* p3 = eptr(e3);
        uint4 d0 = *(const uint4*)p0;
        uint4 d1 = *(const uint4*)p1;
        uint4 d2 = *(const uint4*)p2;
        uint4 d3 = *(const uint4*)p3;
        acc3(d0, e0); acc3(d1, e1); acc3(d2, e2); acc3(d3, e3);
    }
    for (; k < deg; ++k) {
        int e = eids[off + k];
        acc3(*(const uint4*)eptr(e), e);
    }

    float inv = 1.f / fmaxf((float)deg, 1.f);
    auto pack = [&](const float* a) {
        uint4 o;
        o.x = (unsigned)f2bf(a[0] * inv) | ((unsigned)f2bf(a[1] * inv) << 16);
        o.y = (unsigned)f2bf(a[2] * inv) | ((unsigned)f2bf(a[3] * inv) << 16);
        o.z = (unsigned)f2bf(a[4] * inv) | ((unsigned)f2bf(a[5] * inv) << 16);
        o.w = (unsigned)f2bf(a[6] * inv) | ((unsigned)f2bf(a[7] * inv) << 16);
        return o;
    };
    *(uint4*)(agg + (size_t)n * 320 + lane * 8)       = pack(ax);
    *(uint4*)(agg + (size_t)n * 320 + 128 + lane * 8) = pack(bx);
    if (lane < 8)
        *(uint4*)(agg + (size_t)n * 320 + 256 + lane * 8) = pack(ux);
    if (lane == 0) {
        rs[n]          = (float)di * inv;
        rs[NI + n]     = (float)db * inv;
        rs[2 * NI + n] = (float)dc * inv;
    }
}

// ---------------------------------------------------------------------------
// multi-pass bf16 MFMA GEMM (up to 7 passes/job), 2-phase double-buffered
// pipeline, non-persistent grid (round-6 lesson: persistent sweep = long
// tail). Scaled passes (sel>=0): accT += rs_sel[row] * acc at pass end;
// scales preloaded to registers BEFORE the K-loop so no mid-loop vmcnt
// drain. Per-(row,col) bias rs*c added post-loop, pre-restage. Line-
// complete epilogue via wave-private 16KB LDS restage (full 128B lines).
struct GPass { const unsigned short* A; const unsigned short* W; int lda, K, sel; };
struct GJob {
    GPass ps[7];
    const float* colbias; const float* c0; const float* c1; const float* c2;
    const float* rs; float* C;
    int np, M, ldc, nbx, base;
};
struct GJobs { GJob j[3]; };

__global__ __launch_bounds__(256) void gemm_batch_kernel(GJobs jobs) {
    __shared__ __align__(16) unsigned short As[2][128 * 64];
    __shared__ __align__(16) unsigned short Wsh[2][128 * 64];

    const int bid = blockIdx.x;
    const int tid = threadIdx.x;
    const int ji = (bid >= jobs.j[1].base ? 1 : 0) + (bid >= jobs.j[2].base ? 1 : 0);
    const GJob& jb = jobs.j[ji];
    const int rem0 = bid - jb.base;
    const int bx = rem0 % jb.nbx;
    const int by = rem0 / jb.nbx;
    const int m0 = bx * 128;
    const int n0 = by * 128;
    const int M = jb.M;
    const int np = jb.np;

    const int wv = tid >> 6;
    const int wm = wv >> 1, wn = wv & 1;
    const int lane = tid & 63;
    const int lr = lane & 15;
    const int kq = lane >> 4;
    const int lq = lane >> 4;
    const int f4c = lane & 15;
    const int rsub = lane >> 4;

    int nt = 0;
    for (int p = 0; p < np; ++p) nt += jb.ps[p].K >> 6;

    // preloaded per-row scales (job0 only); zero otherwise
    f32x4_t sc0[4], sc1[4], sc2[4];
    float cc0[4], cc1[4], cc2[4];
#pragma unroll
    for (int i = 0; i < 4; ++i) {
        f32x4_t z = {0.f, 0.f, 0.f, 0.f};
        sc0[i] = z; sc1[i] = z; sc2[i] = z;
        cc0[i] = 0.f; cc1[i] = 0.f; cc2[i] = 0.f;
    }
    if (jb.rs) {
#pragma unroll
        for (int i = 0; i < 4; ++i) {
            int row = m0 + wm * 64 + i * 16 + lq * 4;
            sc0[i] = *(const f32x4_t*)&jb.rs[row];
            sc1[i] = *(const f32x4_t*)&jb.rs[NI + row];
            sc2[i] = *(const f32x4_t*)&jb.rs[2 * NI + row];
        }
    }

    auto stage = [&](int t, int buf) {
        int p = 0, tt = t;
        while (tt >= (jb.ps[p].K >> 6)) { tt -= jb.ps[p].K >> 6; ++p; }
        const GPass& P = jb.ps[p];
        const int kb = tt * 64;
#pragma unroll
        for (int pp = 0; pp < 4; ++pp) {
            int s = pp * 256 + tid;
            int r = s >> 3;
            int g = (s & 7) ^ (r & 7);
            int m = m0 + r;
            if (m >= M) m = M - 1;
            int ldsbase = (pp * 256 + wv * 64) * 8;
            gload16(P.A + (size_t)m * P.lda + kb + g * 8, &As[buf][ldsbase]);
            gload16(P.W + (size_t)(n0 + r) * P.K + kb + g * 8, &Wsh[buf][ldsbase]);
        }
    };

    f32x4_t acc[4][4], accT[4][4];
#pragma unroll
    for (int i = 0; i < 4; ++i)
#pragma unroll
        for (int j = 0; j < 4; ++j) {
            f32x4_t z = {0.f, 0.f, 0.f, 0.f};
            acc[i][j] = z; accT[i][j] = z;
        }

    auto flush = [&](f32x4_t (&s)[4]) {
#pragma unroll
        for (int i = 0; i < 4; ++i)
#pragma unroll
            for (int j = 0; j < 4; ++j) {
                accT[i][j] += s[i] * acc[i][j];
                f32x4_t z = {0.f, 0.f, 0.f, 0.f};
                acc[i][j] = z;
            }
    };

    stage(0, 0);
    int cur = 0;
    int pcur = 0;
    int remk = jb.ps[0].K >> 6;
    for (int t = 0; t < nt; ++t) {
        if (t + 1 < nt) {
            stage(t + 1, cur ^ 1);
            asm volatile("s_waitcnt vmcnt(8)" ::: "memory");
        } else {
            asm volatile("s_waitcnt vmcnt(0)" ::: "memory");
        }
        __builtin_amdgcn_sched_barrier(0);
        __builtin_amdgcn_s_barrier();
        __builtin_amdgcn_sched_barrier(0);
#pragma unroll
        for (int s2 = 0; s2 < 2; ++s2) {
            const int slot = ((s2 * 4 + kq) ^ (lr & 7)) * 8;
            bf16x8_t af[4], wf[4];
#pragma unroll
            for (int i = 0; i < 4; ++i)
                af[i] = *(const bf16x8_t*)&As[cur][(wm * 64 + i * 16 + lr) * 64 + slot];
#pragma unroll
            for (int j = 0; j < 4; ++j)
                wf[j] = *(const bf16x8_t*)&Wsh[cur][(wn * 64 + j * 16 + lr) * 64 + slot];
#pragma unroll
            for (int i = 0; i < 4; ++i)
#pragma unroll
                for (int j = 0; j < 4; ++j)
                    acc[i][j] = __builtin_amdgcn_mfma_f32_16x16x32_bf16(
                        af[i], wf[j], acc[i][j], 0, 0, 0);
        }
        __builtin_amdgcn_sched_barrier(0);
        __builtin_amdgcn_s_barrier();
        if (--remk == 0) {
            int se = jb.ps[pcur].sel;
            if (se == 0) flush(sc0);
            else if (se == 1) flush(sc1);
            else if (se == 2) flush(sc2);
            ++pcur;
            if (pcur < np) remk = jb.ps[pcur].K >> 6;
        }
        cur ^= 1;
    }

    // per-(row,col) c-bias terms (post-loop loads; no pipeline impact)
    if (jb.rs) {
#pragma unroll
        for (int j = 0; j < 4; ++j) {
            int col = n0 + wn * 64 + j * 16 + lr;
            cc0[j] = jb.c0[col]; cc1[j] = jb.c1[col]; cc2[j] = jb.c2[col];
        }
    }

    // epilogue: v = acc + accT + sum_se sc*cc, restage in wave-private 16KB
    // LDS, then full-128B-line float4 stores with colbias.
    float* wscr = (float*)((wv & 2) ? (void*)&Wsh[wv & 1][0]
                                    : (void*)&As[wv & 1][0]);
#pragma unroll
    for (int i = 0; i < 4; ++i)
#pragma unroll
        for (int j = 0; j < 4; ++j)
#pragma unroll
            for (int r = 0; r < 4; ++r) {
                float v = acc[i][j][r] + accT[i][j][r]
                        + sc0[i][r] * cc0[j] + sc1[i][r] * cc1[j]
                        + sc2[i][r] * cc2[j];
                wscr[(i * 16 + lq * 4 + r) * 64 + j * 16 + lr] = v;
            }
    asm volatile("s_waitcnt lgkmcnt(0)" ::: "memory");
    __builtin_amdgcn_sched_barrier(0);

    const int colb = n0 + wn * 64 + f4c * 4;
    float4 bv = *(const float4*)&jb.colbias[colb];
#pragma unroll
    for (int p = 0; p < 16; ++p) {
        int rl = p * 4 + rsub;
        float4 v = *(const float4*)&wscr[rl * 64 + f4c * 4];
        v.x += bv.x; v.y += bv.y; v.z += bv.z; v.w += bv.w;
        int gm = m0 + wm * 64 + rl;
        if (gm >= M) continue;
        *(float4*)&jb.C[(size_t)gm * jb.ldc + colb] = v;
    }
}

// ---------------------------------------------------------------------------
extern "C" void kernel_launch(void* const* d_in, const int* in_sizes, int n_in,
                              void* d_out, int out_size, void* d_ws, size_t ws_size,
                              hipStream_t stream) {
    const float* x    = (const float*)d_in[0];
    const float* xb   = (const float*)d_in[1];
    const float* u    = (const float*)d_in[2];
    const int*   ei   = (const int*)d_in[3];
    const int*   eb   = (const int*)d_in[4];
    const int*   ec   = (const int*)d_in[5];
    const int*   bidx = (const int*)d_in[6];
    const int*   cidx = (const int*)d_in[7];
    const float* W_ii = (const float*)d_in[8];   const float* b_ii = (const float*)d_in[9];
    const float* W_bi = (const float*)d_in[10];  const float* b_bi = (const float*)d_in[11];
    const float* W_ci = (const float*)d_in[12];  const float* b_ci = (const float*)d_in[13];
    const float* W_bb = (const float*)d_in[14];  const float* b_bb = (const float*)d_in[15];
    const float* W_cc = (const float*)d_in[16];  const float* b_cc = (const float*)d_in[17];
    const float* W_im = (const float*)d_in[18];  const float* b_im = (const float*)d_in[19];
    const float* W_is = (const float*)d_in[20];  const float* b_is = (const float*)d_in[21];
    const float* W_bm = (const float*)d_in[22];  const float* b_bm = (const float*)d_in[23];
    const float* W_bs = (const float*)d_in[24];  const float* b_bs = (const float*)d_in[25];
    const float* W_cm = (const float*)d_in[26];  const float* b_cm = (const float*)d_in[27];
    const float* W_cs = (const float*)d_in[28];  const float* b_cs = (const float*)d_in[29];

    float* out = (float*)d_out;
    unsigned short* bfr = (unsigned short*)d_ws;

    // ---- ws layout (ushort offsets); ~53.1 MB ----
    unsigned short* x_bf  = bfr;                 //  6,400,000
    unsigned short* xb_bf = bfr + 6400000;       //  2,560,000
    unsigned short* u_bf  = bfr + 8960000;       //    640,000
    unsigned short* aggX  = bfr + 9600000;       // 16,000,000  [50000 x 320]
    unsigned short* wbuf  = bfr + 25600000;      //    311,296
    float* bias  = (float*)(bfr + 25920000);     //  1,536 fp32
    float* rsbuf = (float*)(bfr + 25936000);     //  150,000 fp32

    enum {  // wbuf ushort offsets
        O_wis = 0,       O_wbs = 32768,   O_wcs = 65536,
        O_Gii = 81920,   O_Gbi = 114688,  O_Gci = 147456,
        O_Hii = 163840,  O_Hbi = 196608,  O_Hci = 229376,
        O_Wbmbb = 262144, O_Wcmcc = 294912
    };

    // ---- int scratch in d_out boundary region (overwritten by final GEMM) ----
    int* I       = (int*)(out + (size_t)NI * 256);
    int* ci      = I;
    int* cb      = I + 50000;
    int* cc      = I + 100000;
    int* offsets = I + 150000;
    int* cursor  = I + 200000;
    int* bsum    = I + 250000;   // 256
    int* eids    = I + 250512;   // 530000

    // ---- 0. zero counts ----
    hipMemsetAsync(ci, 0, 3 * NI * sizeof(int), stream);

    // ---- 1. fused prep (conv + packs + bias-combine + weight-combine + count) ----
    WJobs JB;
    auto setj = [&](int i, const float* s, int st, int o, int o2, int N, int K, int d) {
        JB.j[i].src = s; JB.j[i].stride = st; JB.j[i].off = o; JB.j[i].off2 = o2;
        JB.j[i].N = N; JB.j[i].K = K; JB.j[i].dstOff = d;
    };
    setj(0, W_is, 128, 0, -1, 256, 128, O_wis);
    setj(1, W_bs, 128, 0, -1, 256, 128, O_wbs);
    setj(2, W_cs, 64,  0, -1, 256, 64,  O_wcs);

    CJobs CJ;
    auto setc = [&](int i, const float* L, const float* R, int rstr, int ro,
                    int ro2, int N, int d) {
        CJ.j[i].L = L; CJ.j[i].R = R; CJ.j[i].rstr = rstr; CJ.j[i].roff = ro;
        CJ.j[i].roff2 = ro2; CJ.j[i].N = N; CJ.j[i].dstOff = d;
    };
    setc(0, W_im, W_ii, 256, 0,   -1, 128, O_Gii);
    setc(1, W_im, W_bi, 256, 0,   -1, 128, O_Gbi);
    setc(2, W_im, W_ci, 192, 0,   -1, 64,  O_Gci);
    setc(3, W_im, W_ii, 256, 128, -1, 128, O_Hii);
    setc(4, W_im, W_bi, 256, 128, -1, 128, O_Hbi);
    setc(5, W_im, W_ci, 192, 64,  -1, 128, O_Hci);
    setc(6, W_bm, W_bb, 256, 0,  128, 128, O_Wbmbb);
    setc(7, W_cm, W_cc, 128, 0,   64, 64,  O_Wcmcc);

    BiasArgs BA;
    BA.W_im = W_im; BA.W_bm = W_bm; BA.W_cm = W_cm;
    BA.b_ii = b_ii; BA.b_bi = b_bi; BA.b_ci = b_ci;
    BA.b_bb = b_bb; BA.b_cc = b_cc;
    BA.b_is = b_is; BA.b_im = b_im; BA.b_bs = b_bs; BA.b_bm = b_bm;
    BA.b_cs = b_cs; BA.b_cm = b_cm;

    prep_kernel<<<dim3(PREP_NB), dim3(256), 0, stream>>>(
        (const float4*)x, (const float4*)xb, (const float4*)u,
        (ushort4*)x_bf, (ushort4*)xb_bf, (ushort4*)u_bf,
        JB, CJ, BA, wbuf, ei, eb, ec, bidx, cidx, ci, cb, cc, bias);

    // ---- 2. scans + CSR fill ----
    scan1_kernel<<<dim3(SCAN_NB), dim3(256), 0, stream>>>(ci, cb, cc, bsum);
    scan23_kernel<<<dim3(SCAN_NB), dim3(256), 0, stream>>>(ci, cb, cc, bsum,
                                                           offsets, cursor);
    fill_kernel<<<dim3((E_TOT + 255) / 256), dim3(256), 0, stream>>>(
        ei, eb, ec, bidx, cidx, cursor, eids);

    // ---- 3. gather (raw sums + scales) ----
    gather_kernel<<<dim3((NI * 16 + 255) / 256), dim3(256), 0, stream>>>(
        x_bf, xb_bf, u_bf, offsets, ci, cb, cc, eids, aggX, rsbuf);

    // ---- 4. single fused multi-pass GEMM ----
    GJobs LJ;
    auto setp = [&](GPass& p, const unsigned short* A, const unsigned short* W,
                    int lda, int K, int sel) {
        p.A = A; p.W = W; p.lda = lda; p.K = K; p.sel = sel;
    };
    // job0: interior, 7 passes
    {
        GJob& g = LJ.j[0];
        setp(g.ps[0], x_bf, wbuf + O_Hii, 128, 128, 0);
        setp(g.ps[1], x_bf, wbuf + O_Hbi, 128, 128, 1);
        setp(g.ps[2], x_bf, wbuf + O_Hci, 128, 128, 2);
        setp(g.ps[3], aggX,        wbuf + O_Gii, 320, 128, -1);
        setp(g.ps[4], aggX + 128,  wbuf + O_Gbi, 320, 128, -1);
        setp(g.ps[5], aggX + 256,  wbuf + O_Gci, 320, 64,  -1);
        setp(g.ps[6], x_bf, wbuf + O_wis, 128, 128, -1);
        g.colbias = bias; g.c0 = bias + 768; g.c1 = bias + 1024; g.c2 = bias + 1280;
        g.rs = rsbuf; g.C = out;
        g.np = 7; g.M = NI; g.ldc = 256; g.nbx = (NI + 127) / 128; g.base = 0;
    }
    int base1 = LJ.j[0].nbx * 2;
    // job1: boundary, 2 passes
    {
        GJob& g = LJ.j[1];
        setp(g.ps[0], xb_bf, wbuf + O_wbs,   128, 128, -1);
        setp(g.ps[1], xb_bf, wbuf + O_Wbmbb, 128, 128, -1);
        for (int p = 2; p < 7; ++p) setp(g.ps[p], nullptr, nullptr, 0, 64, -1);
        g.colbias = bias + 256; g.c0 = nullptr; g.c1 = nullptr; g.c2 = nullptr;
        g.rs = nullptr; g.C = out + (size_t)NI * 256;
        g.np = 2; g.M = E_BN; g.ldc = 256; g.nbx = (E_BN + 127) / 128; g.base = base1;
    }
    int base2 = base1 + LJ.j[1].nbx * 2;
    // job2: control, 2 passes
    {
        GJob& g = LJ.j[2];
        setp(g.ps[0], u_bf, wbuf + O_wcs,   64, 64, -1);
        setp(g.ps[1], u_bf, wbuf + O_Wcmcc, 64, 64, -1);
        for (int p = 2; p < 7; ++p) setp(g.ps[p], nullptr, nullptr, 0, 64, -1);
        g.colbias = bias + 512; g.c0 = nullptr; g.c1 = nullptr; g.c2 = nullptr;
        g.rs = nullptr; g.C = out + (size_t)(NI + E_BN) * 256;
        g.np = 2; g.M = E_CN; g.ldc = 256; g.nbx = (E_CN + 127) / 128; g.base = base2;
    }
    int total = base2 + LJ.j[2].nbx * 2;
    gemm_batch_kernel<<<dim3(total), dim3(256), 0, stream>>>(LJ);
}

// Round 8
// 317.220 us; speedup vs baseline: 1.1777x; 1.1777x over previous
//
#include <hip/hip_runtime.h>

#define NI 50000
#define E_INTN 500000
#define E_BN 20000
#define E_CN 10000
#define E_TOT (E_INTN + E_BN + E_CN)

typedef __attribute__((ext_vector_type(8))) short bf16x8_t;
typedef __attribute__((ext_vector_type(4))) float f32x4_t;

__device__ __forceinline__ unsigned short f2bf(float f) {
    unsigned int u = __float_as_uint(f);
    unsigned int r = (u + 0x7FFFu + ((u >> 16) & 1u)) >> 16;
    return (unsigned short)r;
}
__device__ __forceinline__ float bf2f(unsigned int h) {
    return __uint_as_float(h << 16);
}

// async global->LDS, 16B per lane; LDS dest = wave-uniform base + lane*16
__device__ __forceinline__ void gload16(const unsigned short* g, unsigned short* l) {
    __builtin_amdgcn_global_load_lds(
        (const __attribute__((address_space(1))) void*)g,
        (__attribute__((address_space(3))) void*)l, 16, 0, 0);
}

// ---------------------------------------------------------------------------
// fused prep: fp32->bf16 conversion, weight packing, count zeroing, bias
// vectors, and fp32 weight-combines Q_b = W_bs + W_bm@(W_bbL+W_bbR),
// Q_c = W_cs + W_cm@(W_ccL+W_ccR) (+ combined bias dots) -- these collapse
// the boundary/control chains to single K=128/K=64 GEMM passes that depend
// only on prep (round-7 lesson: algebra is fine; keep it ONLY where it adds
// no registers/passes to the interior GEMM).
struct WJob { const float* src; int stride, off, off2, N, K, dstOff; };
struct WJobs { WJob j[8]; };
struct CJob {
    const float* L; const float* R; const float* add;
    unsigned short* dst; int rstr, roff, roff2, astr, N;
};
struct CJobs { CJob j[2]; };
struct QArgs {
    const float *W_bm, *W_cm, *b_bb, *b_cc, *b_bs, *b_bm, *b_cs, *b_cm;
    float* qbias;
};

#define CONV_NB 9375   // (2400000+255)/256 float4-groups
#define PW_NB   1024   // 8 pack jobs x 128 blocks
#define ZC_NB   586    // (150000+255)/256
#define CMB_NB  256    // 2 combine jobs x 128 blocks
#define PREP_NB (CONV_NB + PW_NB + ZC_NB + 1 + CMB_NB)

__global__ __launch_bounds__(256) void prep_kernel(
    const float4* __restrict__ x, const float4* __restrict__ xb,
    const float4* __restrict__ u,
    ushort4* __restrict__ x_bf, ushort4* __restrict__ xb_bf,
    ushort4* __restrict__ u_bf,
    WJobs jobs, CJobs cjobs, QArgs qa,
    unsigned short* __restrict__ wbuf,
    int* __restrict__ cnts,
    const float* __restrict__ b_ii, const float* __restrict__ b_bi,
    const float* __restrict__ b_ci, const float* __restrict__ b_bb,
    const float* __restrict__ b_cc, float* __restrict__ bias) {
    int b = blockIdx.x;
    int tid = threadIdx.x;
    if (b < CONV_NB) {
        int g = b * 256 + tid;
        const float4* src; ushort4* dst; int i;
        if (g < 1600000)      { src = x;  dst = x_bf;  i = g; }
        else if (g < 2240000) { src = xb; dst = xb_bf; i = g - 1600000; }
        else if (g < 2400000) { src = u;  dst = u_bf;  i = g - 2240000; }
        else return;
        float4 v = src[i];
        ushort4 o;
        o.x = f2bf(v.x); o.y = f2bf(v.y); o.z = f2bf(v.z); o.w = f2bf(v.w);
        dst[i] = o;
    } else if (b < CONV_NB + PW_NB) {
        int lb = b - CONV_NB;
        WJob jb = jobs.j[lb >> 7];
        int idx = (lb & 127) * 256 + tid;
        if (idx >= jb.N * jb.K) return;
        int n = idx / jb.K;
        int k = idx - n * jb.K;
        float v = jb.src[(size_t)n * jb.stride + jb.off + k];
        if (jb.off2 >= 0) v += jb.src[(size_t)n * jb.stride + jb.off2 + k];
        wbuf[jb.dstOff + (size_t)n * jb.K + k] = f2bf(v);
    } else if (b < CONV_NB + PW_NB + ZC_NB) {
        int i = (b - CONV_NB - PW_NB) * 256 + tid;
        if (i < 3 * NI) cnts[i] = 0;
    } else if (b == CONV_NB + PW_NB + ZC_NB) {
        int t = tid;
        for (int s = 0; s < 4; ++s, t += 256) {
            if (t < 512) {
                float v = 0.f;
                if (t >= 384) v = b_ci[t - 384];
                else if (t >= 256) v = b_bi[t - 256];
                else if (t >= 128) v = b_ii[t - 128];
                bias[t] = v;
            } else if (t < 768) {
                int c = t - 512;
                bias[512 + c] = (c < 128) ? 0.f : b_bb[c - 128];
            } else {
                int c = t - 768;
                bias[768 + c] = (c < 128) ? 0.f : b_cc[c - 128];
            }
        }
        // combined bias: biasB = b_bs + b_bm + W_bm@b_bb ; biasC likewise
        float ab = 0.f, ac = 0.f;
        for (int k = 0; k < 128; ++k) {
            ab += qa.W_bm[tid * 128 + k] * qa.b_bb[k];
            ac += qa.W_cm[tid * 128 + k] * qa.b_cc[k];
        }
        qa.qbias[tid]       = qa.b_bs[tid] + qa.b_bm[tid] + ab;
        qa.qbias[256 + tid] = qa.b_cs[tid] + qa.b_cm[tid] + ac;
    } else {
        int lb = b - CONV_NB - PW_NB - ZC_NB - 1;
        CJob cj = cjobs.j[lb >> 7];
        int idx = (lb & 127) * 256 + tid;
        if (idx >= 256 * cj.N) return;
        int h = (cj.N == 128) ? (idx >> 7) : (idx >> 6);
        int d = idx & (cj.N - 1);
        float v = cj.add[(size_t)h * cj.astr + d];
        const float* Lr = cj.L + (size_t)h * 128;
        for (int k = 0; k < 128; ++k)
            v += Lr[k] * (cj.R[(size_t)k * cj.rstr + cj.roff + d] +
                          cj.R[(size_t)k * cj.rstr + cj.roff2 + d]);
        cj.dst[(size_t)h * cj.N + d] = f2bf(v);
    }
}

// ---------------------------------------------------------------------------
__global__ __launch_bounds__(256) void count_kernel(const int* __restrict__ ei,
                                                    const int* __restrict__ eb,
                                                    const int* __restrict__ ec,
                                                    const int* __restrict__ bidx,
                                                    const int* __restrict__ cidx,
                                                    int* __restrict__ ci,
                                                    int* __restrict__ cb,
                                                    int* __restrict__ cc) {
    int e = blockIdx.x * 256 + threadIdx.x;
    if (e < E_INTN) {
        atomicAdd(&ci[ei[E_INTN + e]], 1);
    } else if (e < E_INTN + E_BN) {
        int j = e - E_INTN;
        int s = eb[j];
        bool m = false;
#pragma unroll
        for (int k = 0; k < 16; ++k) m = m || (s == bidx[k]);
        if (m) atomicAdd(&cb[eb[E_BN + j]], 1);
    } else if (e < E_TOT) {
        int j = e - E_INTN - E_BN;
        int s = ec[j];
        bool m = false;
#pragma unroll
        for (int k = 0; k < 16; ++k) m = m || (s == cidx[k]);
        if (m) atomicAdd(&cc[ec[E_CN + j]], 1);
    }
}

// ---------------------------------------------------------------------------
#define SCAN_NB 196   // ceil(50000/256)

__global__ __launch_bounds__(256) void scan1_kernel(const int* __restrict__ ci,
                                                    const int* __restrict__ cb,
                                                    const int* __restrict__ cc,
                                                    int* __restrict__ bsum) {
    __shared__ int sm[256];
    int n = blockIdx.x * 256 + threadIdx.x;
    int d = (n < NI) ? ci[n] + cb[n] + cc[n] : 0;
    sm[threadIdx.x] = d;
    __syncthreads();
    for (int s = 128; s > 0; s >>= 1) {
        if (threadIdx.x < s) sm[threadIdx.x] += sm[threadIdx.x + s];
        __syncthreads();
    }
    if (threadIdx.x == 0) bsum[blockIdx.x] = sm[0];
}

__global__ __launch_bounds__(256) void scan23_kernel(const int* __restrict__ ci,
                                                     const int* __restrict__ cb,
                                                     const int* __restrict__ cc,
                                                     const int* __restrict__ bsum,
                                                     int* __restrict__ offsets,
                                                     int* __restrict__ cursor) {
    __shared__ int bs[256];
    __shared__ int sm[256];
    int t = threadIdx.x;
    int b = blockIdx.x;
    bs[t] = (t < b) ? bsum[t] : 0;
    __syncthreads();
    for (int s = 128; s > 0; s >>= 1) {
        if (t < s) bs[t] += bs[t + s];
        __syncthreads();
    }
    int ebase = bs[0];
    int n = b * 256 + t;
    int d = (n < NI) ? ci[n] + cb[n] + cc[n] : 0;
    sm[t] = d;
    __syncthreads();
    for (int dd = 1; dd < 256; dd <<= 1) {
        int v = (t >= dd) ? sm[t - dd] : 0;
        __syncthreads();
        sm[t] += v;
        __syncthreads();
    }
    if (n < NI) {
        int excl = sm[t] - d + ebase;
        offsets[n] = excl;
        cursor[n] = excl;
    }
}

// ---------------------------------------------------------------------------
__global__ __launch_bounds__(256) void fill_kernel(const int* __restrict__ ei,
                                                   const int* __restrict__ eb,
                                                   const int* __restrict__ ec,
                                                   const int* __restrict__ bidx,
                                                   const int* __restrict__ cidx,
                                                   int* __restrict__ cursor,
                                                   int* __restrict__ eids) {
    int e = blockIdx.x * 256 + threadIdx.x;
    int t, payload;
    if (e < E_INTN) {
        t = ei[E_INTN + e];
        payload = ei[e];
    } else if (e < E_INTN + E_BN) {
        int j = e - E_INTN;
        int s = eb[j];
        bool m = false;
#pragma unroll
        for (int k = 0; k < 16; ++k) m = m || (s == bidx[k]);
        if (!m) return;
        t = eb[E_BN + j];
        payload = NI + j;
    } else if (e < E_TOT) {
        int j = e - E_INTN - E_BN;
        int s = ec[j];
        bool m = false;
#pragma unroll
        for (int k = 0; k < 16; ++k) m = m || (s == cidx[k]);
        if (!m) return;
        t = ec[E_CN + j];
        payload = NI + E_BN + j;
    } else {
        return;
    }
    int idx = atomicAdd(&cursor[t], 1);
    eids[idx] = payload;
}

// ---------------------------------------------------------------------------
// gather: 16 lanes/node (4 nodes/wave), uint4 (8 bf16) per lane. v3-verbatim.
__device__ __forceinline__ const unsigned short* row_ptr(
    int eid, const unsigned short* Yx, const unsigned short* Yxb,
    const unsigned short* Yu) {
    return (eid < NI) ? Yx + (size_t)eid * 512
         : (eid < NI + E_BN) ? Yxb + (size_t)(eid - NI) * 256
         : Yu + (size_t)(eid - NI - E_BN) * 256;
}

__device__ __forceinline__ void acc_row(float* acc, uint4 d) {
    acc[0] += bf2f(d.x & 0xffff); acc[1] += bf2f(d.x >> 16);
    acc[2] += bf2f(d.y & 0xffff); acc[3] += bf2f(d.y >> 16);
    acc[4] += bf2f(d.z & 0xffff); acc[5] += bf2f(d.z >> 16);
    acc[6] += bf2f(d.w & 0xffff); acc[7] += bf2f(d.w >> 16);
}

__global__ __launch_bounds__(256) void gather_kernel(
    const unsigned short* __restrict__ Yx,
    const unsigned short* __restrict__ Yxb,
    const unsigned short* __restrict__ Yu,
    const int* __restrict__ offsets,
    const int* __restrict__ ci, const int* __restrict__ cb,
    const int* __restrict__ cc, const int* __restrict__ eids,
    unsigned short* __restrict__ agg) {
    int g = blockIdx.x * 256 + threadIdx.x;
    int n = g >> 4;
    int lane = g & 15;
    if (n >= NI) return;
    int off = offsets[n];
    int di = ci[n], db = cb[n], dc = cc[n];
    int deg = di + db + dc;
    float fi = (float)di, fb = (float)db, fc = (float)dc;
    const unsigned short* yrow = Yx + (size_t)n * 512 + lane * 8;
    uint4 vi = *(const uint4*)(yrow + 128);
    uint4 vb = *(const uint4*)(yrow + 256);
    uint4 vc = *(const uint4*)(yrow + 384);
    float acc[8];
    acc[0] = fi * bf2f(vi.x & 0xffff) + fb * bf2f(vb.x & 0xffff) + fc * bf2f(vc.x & 0xffff);
    acc[1] = fi * bf2f(vi.x >> 16)    + fb * bf2f(vb.x >> 16)    + fc * bf2f(vc.x >> 16);
    acc[2] = fi * bf2f(vi.y & 0xffff) + fb * bf2f(vb.y & 0xffff) + fc * bf2f(vc.y & 0xffff);
    acc[3] = fi * bf2f(vi.y >> 16)    + fb * bf2f(vb.y >> 16)    + fc * bf2f(vc.y >> 16);
    acc[4] = fi * bf2f(vi.z & 0xffff) + fb * bf2f(vb.z & 0xffff) + fc * bf2f(vc.z & 0xffff);
    acc[5] = fi * bf2f(vi.z >> 16)    + fb * bf2f(vb.z >> 16)    + fc * bf2f(vc.z >> 16);
    acc[6] = fi * bf2f(vi.w & 0xffff) + fb * bf2f(vb.w & 0xffff) + fc * bf2f(vc.w & 0xffff);
    acc[7] = fi * bf2f(vi.w >> 16)    + fb * bf2f(vb.w >> 16)    + fc * bf2f(vc.w >> 16);
    int k = 0;
    for (; k + 4 <= deg; k += 4) {
        int e0 = eids[off + k],     e1 = eids[off + k + 1];
        int e2 = eids[off + k + 2], e3 = eids[off + k + 3];
        const unsigned short* r0 = row_ptr(e0, Yx, Yxb, Yu);
        const unsigned short* r1 = row_ptr(e1, Yx, Yxb, Yu);
        const unsigned short* r2 = row_ptr(e2, Yx, Yxb, Yu);
        const unsigned short* r3 = row_ptr(e3, Yx, Yxb, Yu);
        uint4 d0 = *(const uint4*)(r0 + lane * 8);
        uint4 d1 = *(const uint4*)(r1 + lane * 8);
        uint4 d2 = *(const uint4*)(r2 + lane * 8);
        uint4 d3 = *(const uint4*)(r3 + lane * 8);
        acc_row(acc, d0); acc_row(acc, d1); acc_row(acc, d2); acc_row(acc, d3);
    }
    for (; k < deg; ++k) {
        const unsigned short* r0 = row_ptr(eids[off + k], Yx, Yxb, Yu);
        acc_row(acc, *(const uint4*)(r0 + lane * 8));
    }
    float inv = 1.f / fmaxf((float)deg, 1.f);
    uint4 o;
    o.x = (unsigned)f2bf(acc[0] * inv) | ((unsigned)f2bf(acc[1] * inv) << 16);
    o.y = (unsigned)f2bf(acc[2] * inv) | ((unsigned)f2bf(acc[3] * inv) << 16);
    o.z = (unsigned)f2bf(acc[4] * inv) | ((unsigned)f2bf(acc[5] * inv) << 16);
    o.w = (unsigned)f2bf(acc[6] * inv) | ((unsigned)f2bf(acc[7] * inv) << 16);
    *(uint4*)(agg + (size_t)n * 128 + lane * 8) = o;
}

// ---------------------------------------------------------------------------
// batched bf16 MFMA GEMM (v3 body: 2-phase double-buffered pipeline +
// line-complete epilogue). Only change vs the 305us version: 5-entry job
// table (forward dispatch also carries the collapsed boundary/control
// final GEMMs, which depend only on prep). 88-VGPR class preserved.
struct GJob {
    const unsigned short* A1; const unsigned short* W1;
    const unsigned short* A2; const unsigned short* W2;
    const float* b1; const float* b2;
    void* C;
    int lda1, K1, lda2, K2, M, ldc, outbf, nbx, base;
};
struct GJobs { GJob j[5]; };

__global__ __launch_bounds__(256) void gemm_batch_kernel(GJobs jobs) {
    __shared__ __align__(16) unsigned short As[2][128 * 64];
    __shared__ __align__(16) unsigned short Wsh[2][128 * 64];

    const int bid = blockIdx.x;
    const int ji = (bid >= jobs.j[1].base ? 1 : 0) + (bid >= jobs.j[2].base ? 1 : 0)
                 + (bid >= jobs.j[3].base ? 1 : 0) + (bid >= jobs.j[4].base ? 1 : 0);
    const GJob& jb = jobs.j[ji];
    const int rem = bid - jb.base;
    const int bx = rem % jb.nbx;
    const int by = rem / jb.nbx;
    const int m0 = bx * 128;
    const int n0 = by * 128;
    const int M = jb.M;

    const int tid = threadIdx.x;
    const int wv = tid >> 6;
    const int wm = wv >> 1, wn = wv & 1;
    const int lane = tid & 63;
    const int lr = lane & 15;
    const int kq = lane >> 4;             // k-subchunk within an MFMA k-step

    const int nch1 = jb.K1 >> 6;
    const int nch2 = (jb.A2 != nullptr) ? (jb.K2 >> 6) : 0;
    const int nt = nch1 + nch2;

    auto stage = [&](int t, int buf) {
        const unsigned short* Ap; const unsigned short* Wp; int lda, K, kb;
        if (t < nch1) { Ap = jb.A1; Wp = jb.W1; lda = jb.lda1; K = jb.K1; kb = t * 64; }
        else          { Ap = jb.A2; Wp = jb.W2; lda = jb.lda2; K = jb.K2; kb = (t - nch1) * 64; }
#pragma unroll
        for (int p = 0; p < 4; ++p) {
            int s = p * 256 + tid;             // 16B slot index 0..1023
            int r = s >> 3;                    // tile row
            int g = (s & 7) ^ (r & 7);         // swizzled global chunk
            int m = m0 + r;
            if (m >= M) m = M - 1;
            int ldsbase = (p * 256 + wv * 64) * 8;   // wave-uniform
            gload16(Ap + (size_t)m * lda + kb + g * 8, &As[buf][ldsbase]);
            gload16(Wp + (size_t)(n0 + r) * K + kb + g * 8, &Wsh[buf][ldsbase]);
        }
    };

    f32x4_t acc[4][4];
#pragma unroll
    for (int i = 0; i < 4; ++i)
#pragma unroll
        for (int j = 0; j < 4; ++j) {
            f32x4_t z = {0.f, 0.f, 0.f, 0.f};
            acc[i][j] = z;
        }

    stage(0, 0);
    int cur = 0;
    for (int t = 0; t < nt; ++t) {
        if (t + 1 < nt) {
            stage(t + 1, cur ^ 1);                       // next tile in flight
            asm volatile("s_waitcnt vmcnt(8)" ::: "memory");   // stage t done
        } else {
            asm volatile("s_waitcnt vmcnt(0)" ::: "memory");
        }
        __builtin_amdgcn_sched_barrier(0);
        __builtin_amdgcn_s_barrier();        // all waves' stage t visible
        __builtin_amdgcn_sched_barrier(0);
#pragma unroll
        for (int s2 = 0; s2 < 2; ++s2) {
            const int slot = ((s2 * 4 + kq) ^ (lr & 7)) * 8;
            bf16x8_t af[4], wf[4];
#pragma unroll
            for (int i = 0; i < 4; ++i)
                af[i] = *(const bf16x8_t*)&As[cur][(wm * 64 + i * 16 + lr) * 64 + slot];
#pragma unroll
            for (int j = 0; j < 4; ++j)
                wf[j] = *(const bf16x8_t*)&Wsh[cur][(wn * 64 + j * 16 + lr) * 64 + slot];
#pragma unroll
            for (int i = 0; i < 4; ++i)
#pragma unroll
                for (int j = 0; j < 4; ++j)
                    acc[i][j] = __builtin_amdgcn_mfma_f32_16x16x32_bf16(
                        af[i], wf[j], acc[i][j], 0, 0, 0);
        }
        __builtin_amdgcn_sched_barrier(0);
        __builtin_amdgcn_s_barrier();        // reads done before buf reuse
        cur ^= 1;
    }

    // ---- epilogue: wave-private 16KB LDS stage (64x64 fp32, stride 64),
    // then full-line global stores (128B-complete).
    float* wscr = (float*)((wv & 2) ? (void*)&Wsh[wv & 1][0]
                                    : (void*)&As[wv & 1][0]);
    const int lq = lane >> 4;
#pragma unroll
    for (int i = 0; i < 4; ++i)
#pragma unroll
        for (int j = 0; j < 4; ++j)
#pragma unroll
            for (int r = 0; r < 4; ++r)
                wscr[(i * 16 + lq * 4 + r) * 64 + j * 16 + lr] = acc[i][j][r];
    asm volatile("s_waitcnt lgkmcnt(0)" ::: "memory");
    __builtin_amdgcn_sched_barrier(0);

    const int f4c = lane & 15;            // float4 column 0..15
    const int rsub = lane >> 4;           // row-within-4
    const int colb = n0 + wn * 64 + f4c * 4;
    float4 bv = make_float4(0.f, 0.f, 0.f, 0.f);
    if (jb.b1) {
        float4 t1 = *(const float4*)&jb.b1[colb];
        bv.x += t1.x; bv.y += t1.y; bv.z += t1.z; bv.w += t1.w;
    }
    if (jb.b2) {
        float4 t2 = *(const float4*)&jb.b2[colb];
        bv.x += t2.x; bv.y += t2.y; bv.z += t2.z; bv.w += t2.w;
    }
#pragma unroll
    for (int p = 0; p < 16; ++p) {
        int rl = p * 4 + rsub;            // local row 0..63
        float4 v = *(const float4*)&wscr[rl * 64 + f4c * 4];
        v.x += bv.x; v.y += bv.y; v.z += bv.z; v.w += bv.w;
        int gm = m0 + wm * 64 + rl;
        if (gm >= M) continue;
        if (jb.outbf) {
            ushort4 o;
            o.x = f2bf(v.x); o.y = f2bf(v.y); o.z = f2bf(v.z); o.w = f2bf(v.w);
            *(ushort4*)&((unsigned short*)jb.C)[(size_t)gm * jb.ldc + colb] = o;
        } else {
            *(float4*)&((float*)jb.C)[(size_t)gm * jb.ldc + colb] = v;
        }
    }
}

// ---------------------------------------------------------------------------
extern "C" void kernel_launch(void* const* d_in, const int* in_sizes, int n_in,
                              void* d_out, int out_size, void* d_ws, size_t ws_size,
                              hipStream_t stream) {
    const float* x    = (const float*)d_in[0];
    const float* xb   = (const float*)d_in[1];
    const float* u    = (const float*)d_in[2];
    const int*   ei   = (const int*)d_in[3];
    const int*   eb   = (const int*)d_in[4];
    const int*   ec   = (const int*)d_in[5];
    const int*   bidx = (const int*)d_in[6];
    const int*   cidx = (const int*)d_in[7];
    const float* W_ii = (const float*)d_in[8];   const float* b_ii = (const float*)d_in[9];
    const float* W_bi = (const float*)d_in[10];  const float* b_bi = (const float*)d_in[11];
    const float* W_ci = (const float*)d_in[12];  const float* b_ci = (const float*)d_in[13];
    const float* W_bb = (const float*)d_in[14];  const float* b_bb = (const float*)d_in[15];
    const float* W_cc = (const float*)d_in[16];  const float* b_cc = (const float*)d_in[17];
    const float* W_im = (const float*)d_in[18];  const float* b_im = (const float*)d_in[19];
    const float* W_is = (const float*)d_in[20];  const float* b_is = (const float*)d_in[21];
    const float* W_bm = (const float*)d_in[22];  const float* b_bm = (const float*)d_in[23];
    const float* W_bs = (const float*)d_in[24];  const float* b_bs = (const float*)d_in[25];
    const float* W_cm = (const float*)d_in[26];  const float* b_cm = (const float*)d_in[27];
    const float* W_cs = (const float*)d_in[28];  const float* b_cs = (const float*)d_in[29];

    float* out = (float*)d_out;
    unsigned short* bfr = (unsigned short*)d_ws;

    // ---- ws layout (ushort offsets); same high-water as v3 (~99.2 MB) ----
    unsigned short* x_bf  = bfr;                 //  6,400,000
    unsigned short* xb_bf = bfr + 6400000;       //  2,560,000
    unsigned short* u_bf  = bfr + 8960000;       //    640,000
    unsigned short* Yx    = bfr + 9600000;       // 25,600,000  [50000 x 512]
    unsigned short* Yxb   = bfr + 35200000;      //  [20000 x 256], cols 0:128 used
    unsigned short* Yu    = bfr + 40320000;      //  [10000 x 256], cols 0:128 used
    unsigned short* agg   = bfr + 42880000;      //  6,400,000  [50000 x 128]
    unsigned short* wbuf  = bfr + 49280000;      //    294,912 (subset used)
    float* bias  = (float*)(bfr + 49600000);     //  1024 fp32
    float* bias_x  = bias;
    float* bias_xb = bias + 512;
    float* bias_u  = bias + 768;

    // Q_b/Q_c/qbias live in the agg region: written by prep, read by the
    // forward dispatch, dead before gather overwrites agg.
    unsigned short* qb    = agg;                 // 32,768  [256 x 128]
    unsigned short* qc    = agg + 32768;         // 16,384  [256 x 64]
    float*          qbias = (float*)(agg + 49152);   // 512 fp32

    enum {
        O_WX  = 0,      O_WXB = 65536,  O_WU  = 81920,
        O_wis = 90112,  O_wim = 122880
    };

    // ---- int scratch at out[0] (interior region; clobbered only by the
    // final GEMM dispatch, which runs after gather) ----
    int* I       = (int*)out;
    int* ci      = I;
    int* cb      = I + 50000;
    int* cc      = I + 100000;
    int* offsets = I + 150000;
    int* cursor  = I + 200000;
    int* bsum    = I + 250000;   // 256
    int* eids    = I + 250512;   // 530000

    // ---- 1. fused prep ----
    WJobs JB;
    auto setj = [&](int i, const float* s, int st, int o, int o2, int N, int K, int d) {
        JB.j[i].src = s; JB.j[i].stride = st; JB.j[i].off = o; JB.j[i].off2 = o2;
        JB.j[i].N = N; JB.j[i].K = K; JB.j[i].dstOff = d;
    };
    setj(0, W_ii, 256, 0,   -1, 128, 128, O_WX);           // A slice
    setj(1, W_ii, 256, 128, -1, 128, 128, O_WX + 16384);   // Bii
    setj(2, W_bi, 256, 128, -1, 128, 128, O_WX + 32768);   // Bbi
    setj(3, W_ci, 192, 64,  -1, 128, 128, O_WX + 49152);   // Bci
    setj(4, W_bi, 256, 0,   -1, 128, 128, O_WXB);          // xbp
    setj(5, W_ci, 192, 0,   -1, 128, 64,  O_WU);           // ucp
    setj(6, W_is, 128, 0,   -1, 256, 128, O_wis);
    setj(7, W_im, 128, 0,   -1, 256, 128, O_wim);

    CJobs CJ;
    // Q_b = W_bs + W_bm @ (W_bb[:,:128] + W_bb[:,128:])
    CJ.j[0].L = W_bm; CJ.j[0].R = W_bb; CJ.j[0].add = W_bs; CJ.j[0].dst = qb;
    CJ.j[0].rstr = 256; CJ.j[0].roff = 0; CJ.j[0].roff2 = 128;
    CJ.j[0].astr = 128; CJ.j[0].N = 128;
    // Q_c = W_cs + W_cm @ (W_cc[:,:64] + W_cc[:,64:])
    CJ.j[1].L = W_cm; CJ.j[1].R = W_cc; CJ.j[1].add = W_cs; CJ.j[1].dst = qc;
    CJ.j[1].rstr = 128; CJ.j[1].roff = 0; CJ.j[1].roff2 = 64;
    CJ.j[1].astr = 64; CJ.j[1].N = 64;

    QArgs QA;
    QA.W_bm = W_bm; QA.W_cm = W_cm; QA.b_bb = b_bb; QA.b_cc = b_cc;
    QA.b_bs = b_bs; QA.b_bm = b_bm; QA.b_cs = b_cs; QA.b_cm = b_cm;
    QA.qbias = qbias;

    prep_kernel<<<dim3(PREP_NB), dim3(256), 0, stream>>>(
        (const float4*)x, (const float4*)xb, (const float4*)u,
        (ushort4*)x_bf, (ushort4*)xb_bf, (ushort4*)u_bf,
        JB, CJ, QA, wbuf, ci, b_ii, b_bi, b_ci, b_bb, b_cc, bias);

    // ---- 2. counts + scans + CSR fill ----
    count_kernel<<<dim3((E_TOT + 255) / 256), dim3(256), 0, stream>>>(
        ei, eb, ec, bidx, cidx, ci, cb, cc);
    scan1_kernel<<<dim3(SCAN_NB), dim3(256), 0, stream>>>(ci, cb, cc, bsum);
    scan23_kernel<<<dim3(SCAN_NB), dim3(256), 0, stream>>>(ci, cb, cc, bsum,
                                                           offsets, cursor);
    fill_kernel<<<dim3((E_TOT + 255) / 256), dim3(256), 0, stream>>>(
        ei, eb, ec, bidx, cidx, cursor, eids);

    auto setg = [&](GJob& g,
                    const unsigned short* A1, int lda1, int K1, const unsigned short* W1,
                    const unsigned short* A2, int lda2, int K2, const unsigned short* W2,
                    const float* bb1, const float* bb2, int outbf,
                    void* C, int M, int N, int ldc, int base) {
        g.A1 = A1; g.W1 = W1; g.A2 = A2; g.W2 = W2;
        g.b1 = bb1; g.b2 = bb2; g.C = C;
        g.lda1 = lda1; g.K1 = K1; g.lda2 = lda2; g.K2 = K2;
        g.M = M; g.ldc = ldc; g.outbf = outbf;
        g.nbx = (M + 127) / 128; g.base = base;
        return g.nbx * (N / 128);
    };

    // ---- 3. forward GEMMs + collapsed boundary/control finals (5 jobs) ----
    GJobs FJ;
    int fb = 0;
    fb += setg(FJ.j[0], x_bf, 128, 128, wbuf + O_WX, nullptr, 0, 0, nullptr,
               bias_x, nullptr, 1, Yx, NI, 512, 512, fb);
    fb += setg(FJ.j[1], xb_bf, 128, 128, wbuf + O_WXB, nullptr, 0, 0, nullptr,
               bias_xb, nullptr, 1, Yxb, E_BN, 128, 256, fb);     // xbp only
    fb += setg(FJ.j[2], u_bf, 64, 64, wbuf + O_WU, nullptr, 0, 0, nullptr,
               bias_u, nullptr, 1, Yu, E_CN, 128, 256, fb);       // ucp only
    fb += setg(FJ.j[3], xb_bf, 128, 128, qb, nullptr, 0, 0, nullptr,
               qbias, nullptr, 0, out + (size_t)NI * 256, E_BN, 256, 256, fb);
    fb += setg(FJ.j[4], u_bf, 64, 64, qc, nullptr, 0, 0, nullptr,
               qbias + 256, nullptr, 0, out + (size_t)(NI + E_BN) * 256,
               E_CN, 256, 256, fb);
    gemm_batch_kernel<<<dim3(fb), dim3(256), 0, stream>>>(FJ);

    // ---- 4. gather ----
    gather_kernel<<<dim3((NI * 16 + 255) / 256), dim3(256), 0, stream>>>(
        Yx, Yxb, Yu, offsets, ci, cb, cc, eids, agg);

    // ---- 5. final interior GEMM (clobbers scratch at out[0] -- after gather) ----
    GJobs LJ;
    int lb = 0;
    lb += setg(LJ.j[0], x_bf, 128, 128, wbuf + O_wis, agg, 128, 128, wbuf + O_wim,
               b_is, b_im, 0, out, NI, 256, 256, lb);
    for (int k = 1; k < 5; ++k) { LJ.j[k] = LJ.j[0]; LJ.j[k].base = 0x7fffffff; }
    gemm_batch_kernel<<<dim3(lb), dim3(256), 0, stream>>>(LJ);
}